// Round 3
// baseline (676.428 us; speedup 1.0000x reference)
//
#include <hip/hip_runtime.h>
#include <math.h>

#define CCH 128
#define HH 64
#define WW 64
#define NSAMP 16
#define SHD 17
#define NSHIFT (SHD*SHD)   // 289

// ---- workspace layout (floats unless noted) ----
#define OFF_RAW    0                         // 16*16*289 = 73984 floats
#define OFF_NORM   73984                     // 16 floats (grd sumsq)
#define OFF_ENERGY 74000                     // 16*64*64 floats
#define OFF_SCALE  139536                    // 16*289 floats
#define OFF_SATB_B 576640                    // bytes; bf16 satb/grdb
#define TENSOR_U16 8388608u                  // ushorts per tensor
#define SLICE_U16  1048576u                  // ushorts per c-slice (16 ch)
#define ZERO_BYTES 296000                    // raw + norm

typedef __bf16 bf16x8 __attribute__((ext_vector_type(8)));
typedef float floatx4 __attribute__((ext_vector_type(4)));
typedef unsigned short ushort8 __attribute__((ext_vector_type(8)));

#define AS1 __attribute__((address_space(1)))
#define AS3 __attribute__((address_space(3)))

__device__ inline unsigned short f2bf(float f) {
    unsigned x = __float_as_uint(f);
    unsigned r = x + 0x7FFFu + ((x >> 16) & 1u);   // RNE
    return (unsigned short)(r >> 16);
}

// ---------------- K1: convert + transpose + norms/energy ----------------
// out layout (per tensor): [csl(8)][ ((h*64+w)*16 + n)*16 + c8*8 + c ] bf16
// grid: 2 tensors * 16 samples * 64 h = 2048 blocks, 256 threads
__global__ __launch_bounds__(256) void k_prep(const float* __restrict__ sat,
                                              const float* __restrict__ grd,
                                              float* __restrict__ ws) {
    __shared__ unsigned short tile[64 * 128];   // [w][16 chunks xor-swizzled][8]
    __shared__ float ered[4][64];
    int b = blockIdx.x;
    int tensor = b >> 10, n = (b >> 6) & 15, h = b & 63;
    const float* src = tensor ? grd : sat;
    unsigned short* dst = (unsigned short*)((char*)ws + OFF_SATB_B) + (size_t)tensor * TENSOR_U16;
    int t = threadIdx.x;
    int w = t & 63, cg4 = t >> 6;

    float esum = 0.f;
    #pragma unroll
    for (int it = 0; it < 4; ++it) {
        int cg = it * 4 + cg4;      // c-octet index (8 channels)
        int cb = cg * 8;
        ushort8 pack;
        #pragma unroll
        for (int j = 0; j < 8; ++j) {
            float v = src[(((size_t)n * CCH + cb + j) * HH + h) * WW + w];
            esum = fmaf(v, v, esum);
            pack[j] = f2bf(v);
        }
        int chunk = cg ^ (w & 15);
        *(ushort8*)&tile[(w * 16 + chunk) * 8] = pack;
    }
    ered[cg4][w] = esum;
    __syncthreads();
    if (t < 64) {
        float e = ered[0][t] + ered[1][t] + ered[2][t] + ered[3][t];
        if (tensor == 0) {
            ws[OFF_ENERGY + ((size_t)n * HH + h) * WW + t] = e;
        } else {
            #pragma unroll
            for (int off = 32; off; off >>= 1) e += __shfl_xor(e, off);
            if (t == 0) atomicAdd(&ws[OFF_NORM + n], e);
        }
    }
    // write transposed: chunk cg -> csl = cg>>1, c8 = cg&1
    int wq = t >> 2, q = t & 3;
    size_t obase = ((size_t)(h * 64 + wq) * 16 + n) * 16;
    #pragma unroll
    for (int c4 = 0; c4 < 4; ++c4) {
        int cg = q * 4 + c4;
        int csl = cg >> 1, c8 = cg & 1;
        int chunk = cg ^ (wq & 15);
        ushort8 val = *(ushort8*)&tile[(wq * 16 + chunk) * 8];
        *(ushort8*)&dst[(size_t)csl * SLICE_U16 + obase + c8 * 8] = val;
    }
}

// ---------------- K2: windowed energy -> scale ----------------
__global__ void k_scale(float* __restrict__ ws) {
    const float* energy = ws + OFF_ENERGY;
    float* scale = ws + OFF_SCALE;
    int b = blockIdx.x;            // 16*289
    int m = b / NSHIFT, s = b % NSHIFT;
    int i = s / SHD, j = s % SHD;
    int y0 = max(0, i - 8), y1 = min(HH, i + 56);
    int x0 = max(0, j - 8), x1 = min(WW, j + 56);
    int ny = y1 - y0, nx = x1 - x0, tot = ny * nx;
    float acc = 0.f;
    for (int idx = threadIdx.x; idx < tot; idx += blockDim.x) {
        int yy = y0 + idx / nx, xx = x0 + idx % nx;
        acc += energy[(m * HH + yy) * WW + xx];
    }
    #pragma unroll
    for (int off = 32; off; off >>= 1) acc += __shfl_xor(acc, off);
    __shared__ float red[4];
    int lane = threadIdx.x & 63, wv = threadIdx.x >> 6;
    if (lane == 0) red[wv] = acc;
    __syncthreads();
    if (threadIdx.x == 0) {
        float tsum = red[0] + red[1] + red[2] + red[3];
        scale[b] = 1.f / fmaxf(sqrtf(tsum), 1e-12f);
    }
}

// ---------------- K3: MFMA cross-correlation (double-buffered, w-in-K) ----
// grid: b -> csl = b%8 (XCD affinity), dyi = (b/8)%17, hc = b/8/17
// 256 thr = 4 waves; wave wv owns grd w in [wv*16, wv*16+16) as 8 w-pairs.
// K = 32 = 16 channels x 2 adjacent w. LDS: 2 buffers of 64 w-slots (512 B
// each) + zero guard slots; layout slot(p,w) = p*72 + 8 + w.
__global__ __launch_bounds__(256, 2) void k_corr(const unsigned short* __restrict__ satb,
                                                 const unsigned short* __restrict__ grdb,
                                                 float* __restrict__ ws) {
    __shared__ alignas(16) unsigned char smem[152 * 512];   // 77824 B
    int b = blockIdx.x;
    int csl = b & 7;
    int r2  = b >> 3;
    int dyi = r2 % 17;
    int hc  = r2 / 17;             // 0..15
    int t = threadIdx.x;
    int wv = t >> 6, l = t & 63;
    int m16 = l & 15, q = l >> 4;
    int jl = q >> 1, c8 = q & 1;
    int wbase = wv * 16;

    const unsigned short* sats = satb + (size_t)csl * SLICE_U16;
    const unsigned short* grds = grdb + (size_t)csl * SLICE_U16;

    // zero the 3 guard regions (4096 B each at 0 / 36864 / 73728)
    for (int i = t; i < 768; i += 256) {
        int reg = i >> 8, off = (i & 255) * 16;
        *(floatx4*)(smem + reg * 36864 + off) = (floatx4)0.f;
    }

    floatx4 acc[17];
    #pragma unroll
    for (int d = 0; d < 17; ++d) acc[d] = (floatx4)0.f;

    int hs0 = hc * 4 + dyi - 8;
    int lw = l >> 5, lm = (l >> 1) & 15, lc = l & 1;   // staging lane decode

    // stage sat row hs into buffer p (32 KB, 8 issues/wave of 1 KB)
    #define STAGE(hs, p)                                                          \
        do {                                                                      \
            _Pragma("unroll")                                                     \
            for (int i_ = 0; i_ < 8; ++i_) {                                      \
                int s0_ = wbase + 2 * i_;                                         \
                const unsigned short* g_ = sats +                                 \
                    (((size_t)((hs) * 64 + s0_ + lw) * 16 + lm) * 16 + lc * 8);   \
                __builtin_amdgcn_global_load_lds((AS1 void*)(unsigned short*)g_,  \
                    (AS3 void*)(smem + (p) * 36864 + (8 + s0_) * 512), 16, 0, 0); \
            }                                                                     \
        } while (0)

    if ((unsigned)hs0 < (unsigned)HH) STAGE(hs0, 0);

    for (int hh = 0; hh < 4; ++hh) {
        __syncthreads();                       // staged buf[hh&1] ready
        int hsn = hs0 + hh + 1;
        if (hh < 3 && (unsigned)hsn < (unsigned)HH) STAGE(hsn, (hh + 1) & 1);
        int hs = hs0 + hh;
        if ((unsigned)hs < (unsigned)HH) {     // block-uniform
            int h = hc * 4 + hh;
            bf16x8 Bf[8];
            #pragma unroll
            for (int bi = 0; bi < 8; ++bi) {
                int wg0 = wbase + 2 * bi;
                Bf[bi] = *(const bf16x8*)(grds +
                    (((size_t)(h * 64 + wg0 + jl) * 16 + m16) * 16 + c8 * 8));
            }
            const unsigned char* aptr = smem + (hh & 1) * 36864 + jl * 512 + m16 * 32 + c8 * 16;
            #pragma unroll
            for (int wo = 0; wo < 31; ++wo) {     // ws0 = wbase - 8 + wo
                bf16x8 A = *(const bf16x8*)(aptr + (wbase + wo) * 512);
                #pragma unroll
                for (int bi = 0; bi < 8; ++bi) {
                    int dxi = wo - 2 * bi;        // compile-time after unroll
                    if (dxi >= 0 && dxi <= 16)
                        acc[dxi] = __builtin_amdgcn_mfma_f32_16x16x32_bf16(A, Bf[bi], acc[dxi], 0, 0, 0);
                }
            }
        }
    }
    #undef STAGE

    // cross-wave reduce in LDS, wave 0 commits via atomics
    __syncthreads();
    if (wv > 0) {
        #pragma unroll
        for (int dxi = 0; dxi < 17; ++dxi)
            *(floatx4*)(smem + (((wv - 1) * 17 + dxi) * 64 + l) * 16) = acc[dxi];
    }
    __syncthreads();
    if (wv == 0) {
        float* raw = ws + OFF_RAW;
        #pragma unroll
        for (int dxi = 0; dxi < 17; ++dxi) {
            floatx4 v = acc[dxi];
            #pragma unroll
            for (int p = 0; p < 3; ++p)
                v += *(floatx4*)(smem + ((p * 17 + dxi) * 64 + l) * 16);
            int s = dyi * 17 + dxi;
            #pragma unroll
            for (int r = 0; r < 4; ++r) {
                int m = q * 4 + r;
                atomicAdd(&raw[(size_t)(m * 16 + m16) * NSHIFT + s], v[r]);
            }
        }
    }
}

// ---------------- K4: epilogue -> 3 scalars ----------------
__global__ void k_final(const float* __restrict__ ws, float* __restrict__ out) {
    const float* raw   = ws + OFF_RAW;
    const float* scale = ws + OFF_SCALE;
    const float* norms = ws + OFF_NORM;
    __shared__ float dist_s[256];
    __shared__ float pos_s[16];
    __shared__ float red[256];
    __shared__ float minv[16];
    int t = threadIdx.x;          // t = m*16 + n
    int m = t >> 4, n = t & 15;

    float best = -1e30f;
    const float* rp = raw + (size_t)t * NSHIFT;
    const float* sp = scale + m * NSHIFT;
    for (int s = 0; s < NSHIFT; ++s) best = fmaxf(best, rp[s] * sp[s]);
    float Ng  = sqrtf(norms[n]);
    float sim = best / fmaxf(Ng, 1e-12f);
    float d   = 2.f - 2.f * sim;
    dist_s[t] = d;
    if (m == n) pos_s[m] = d;
    __syncthreads();

    float x1 = (pos_s[n] - d) * 10.f;
    float x2 = (pos_s[m] - d) * 10.f;
    float sp1 = x1 > 20.f ? x1 : log1pf(expf(x1));
    float sp2 = x2 > 20.f ? x2 : log1pf(expf(x2));
    red[t] = sp1 + sp2;
    __syncthreads();
    for (int off = 128; off; off >>= 1) {
        if (t < off) red[t] += red[t + off];
        __syncthreads();
    }
    if (t < 16) {
        float mv = 1e30f;
        for (int nn = 0; nn < 16; ++nn) mv = fminf(mv, dist_s[t * 16 + nn]);
        minv[t] = mv;
    }
    __syncthreads();
    if (t == 0) {
        float psum = 0.f, msum = 0.f;
        for (int qq = 0; qq < 16; ++qq) { psum += pos_s[qq]; msum += minv[qq]; }
        out[0] = red[0] / 48.f;
        out[1] = psum / 16.f;
        out[2] = msum / 16.f;
    }
}

extern "C" void kernel_launch(void* const* d_in, const int* in_sizes, int n_in,
                              void* d_out, int out_size, void* d_ws, size_t ws_size,
                              hipStream_t stream) {
    const float* sat = (const float*)d_in[0];
    const float* grd = (const float*)d_in[1];
    float* out = (float*)d_out;
    float* ws  = (float*)d_ws;
    const unsigned short* satb = (const unsigned short*)((char*)d_ws + OFF_SATB_B);
    const unsigned short* grdb = satb + TENSOR_U16;

    hipMemsetAsync(d_ws, 0, ZERO_BYTES, stream);
    k_prep <<<2048,           256, 0, stream>>>(sat, grd, ws);
    k_scale<<<16 * NSHIFT,    256, 0, stream>>>(ws);
    k_corr <<<17 * 16 * 8,    256, 0, stream>>>(satb, grdb, ws);
    k_final<<<1,              256, 0, stream>>>(ws, out);
}

// Round 4
// 436.146 us; speedup vs baseline: 1.5509x; 1.5509x over previous
//
#include <hip/hip_runtime.h>
#include <math.h>

#define CCH 128
#define HH 64
#define WW 64
#define SHD 17
#define NSHIFT (SHD*SHD)   // 289

// ---- workspace layout ----
// floats (index): raw 73984 | norm 16 | energy 65536 | scale 4624
#define OFF_RAW    0
#define OFF_NORM   73984
#define OFF_ENERGY 74000
#define OFF_SCALE  139536
// bytes:
#define OFF_SATP_B 576640                         // padded sat bf16: 8 slices x [h64][slot80][n16][c16]
#define SATP_SLICE_U16 (64*80*16*16)              // 1310720
#define OFF_GRDB_B (OFF_SATP_B + 8*SATP_SLICE_U16*2)        // 21548160
#define GRD_SLICE_U16 (64*64*16*16)               // 1048576
#define OFF_PART_B (OFF_GRDB_B + 8*GRD_SLICE_U16*2)         // 38325376
#define PART_F_BLK 4352                           // 17*256 floats per corr block
#define NBLK_CORR (17*64)                         // 1088  (dyi * (csl8 x hq8))
#define ZERO_BYTES 296064                         // raw + norm

typedef __bf16 bf16x8 __attribute__((ext_vector_type(8)));
typedef float floatx4 __attribute__((ext_vector_type(4)));
typedef unsigned short ushort8 __attribute__((ext_vector_type(8)));

__device__ inline unsigned short f2bf(float f) {
    unsigned x = __float_as_uint(f);
    unsigned r = x + 0x7FFFu + ((x >> 16) & 1u);   // RNE
    return (unsigned short)(r >> 16);
}

// ---------------- K1: convert + transpose + norms/energy ----------------
// sat -> padded [csl][h][slot=8+w][n][c], grd -> [csl][h][w][n][c]
// grid: 2 tensors * 16 samples * 64 h = 2048 blocks, 256 threads
__global__ __launch_bounds__(256) void k_prep(const float* __restrict__ sat,
                                              const float* __restrict__ grd,
                                              float* __restrict__ ws) {
    __shared__ unsigned short tile[64 * 128];   // [w][16 chunks xor-swizzled][8]
    __shared__ float ered[4][64];
    int b = blockIdx.x;
    int tensor = b >> 10, n = (b >> 6) & 15, h = b & 63;
    const float* src = tensor ? grd : sat;
    unsigned short* dstS = (unsigned short*)((char*)ws + OFF_SATP_B);
    unsigned short* dstG = (unsigned short*)((char*)ws + OFF_GRDB_B);
    int t = threadIdx.x;
    int w = t & 63, cg4 = t >> 6;

    float esum = 0.f;
    #pragma unroll
    for (int it = 0; it < 4; ++it) {
        int cg = it * 4 + cg4;      // c-octet index (8 channels)
        int cb = cg * 8;
        ushort8 pack;
        #pragma unroll
        for (int j = 0; j < 8; ++j) {
            float v = src[(((size_t)n * CCH + cb + j) * HH + h) * WW + w];
            esum = fmaf(v, v, esum);
            pack[j] = f2bf(v);
        }
        int chunk = cg ^ (w & 15);
        *(ushort8*)&tile[(w * 16 + chunk) * 8] = pack;
    }
    ered[cg4][w] = esum;
    __syncthreads();
    if (t < 64) {
        float e = ered[0][t] + ered[1][t] + ered[2][t] + ered[3][t];
        if (tensor == 0) {
            ws[OFF_ENERGY + ((size_t)n * HH + h) * WW + t] = e;
        } else {
            #pragma unroll
            for (int off = 32; off; off >>= 1) e += __shfl_xor(e, off);
            if (t == 0) atomicAdd(&ws[OFF_NORM + n], e);
        }
    }
    // zero w-pad slots of sat (slots 0..7 and 72..79) for this (h, n)
    if (tensor == 0) {
        int cslz = t >> 5, i5 = t & 31;
        int s8 = i5 & 15, cz = i5 >> 4;
        int p = (s8 < 8) ? s8 : (s8 + 64);
        *(ushort8*)&dstS[(size_t)cslz * SATP_SLICE_U16 +
                         (((size_t)h * 80 + p) * 16 + n) * 16 + cz * 8] = (ushort8)0;
    }
    // transposed data write
    int wq = t >> 2, q = t & 3;
    #pragma unroll
    for (int c4 = 0; c4 < 4; ++c4) {
        int cg = q * 4 + c4;
        int csl = cg >> 1, c8 = cg & 1;
        int chunk = cg ^ (wq & 15);
        ushort8 val = *(ushort8*)&tile[(wq * 16 + chunk) * 8];
        if (tensor == 0) {
            dstS[(size_t)csl * SATP_SLICE_U16 +
                 (((size_t)h * 80 + 8 + wq) * 16 + n) * 16 + c8 * 8] =
                 val[0],  // dummy to avoid miscompile? no — use vector store below
            *(ushort8*)&dstS[(size_t)csl * SATP_SLICE_U16 +
                             (((size_t)h * 80 + 8 + wq) * 16 + n) * 16 + c8 * 8] = val;
        } else {
            *(ushort8*)&dstG[(size_t)csl * GRD_SLICE_U16 +
                             (((size_t)h * 64 + wq) * 16 + n) * 16 + c8 * 8] = val;
        }
    }
}

// ---------------- K2: windowed energy -> scale ----------------
__global__ void k_scale(float* __restrict__ ws) {
    const float* energy = ws + OFF_ENERGY;
    float* scale = ws + OFF_SCALE;
    int b = blockIdx.x;            // 16*289
    int m = b / NSHIFT, s = b % NSHIFT;
    int i = s / SHD, j = s % SHD;
    int y0 = max(0, i - 8), y1 = min(HH, i + 56);
    int x0 = max(0, j - 8), x1 = min(WW, j + 56);
    int ny = y1 - y0, nx = x1 - x0, tot = ny * nx;
    float acc = 0.f;
    for (int idx = threadIdx.x; idx < tot; idx += blockDim.x) {
        int yy = y0 + idx / nx, xx = x0 + idx % nx;
        acc += energy[(m * HH + yy) * WW + xx];
    }
    #pragma unroll
    for (int off = 32; off; off >>= 1) acc += __shfl_xor(acc, off);
    __shared__ float red[4];
    int lane = threadIdx.x & 63, wv = threadIdx.x >> 6;
    if (lane == 0) red[wv] = acc;
    __syncthreads();
    if (threadIdx.x == 0) {
        float tsum = red[0] + red[1] + red[2] + red[3];
        scale[b] = 1.f / fmaxf(sqrtf(tsum), 1e-12f);
    }
}

// ---------------- K3: MFMA cross-correlation, no barriers, no staging ----
// grid: b -> dyi = b>>6, csl = (b>>3)&7 (XCD affinity), hq = b&7 (8 h each)
// 4 waves; wave wv owns grd w in [wv*16, wv*16+16) as 8 w-pairs; K=32=16c x 2w.
// A read direct from padded satp (L2-resident); acc[17] floatx4; LDS only for
// the cross-wave reduce; plain partial store (no global atomics).
__global__ __launch_bounds__(256, 3) void k_corr(const unsigned short* __restrict__ satp,
                                                 const unsigned short* __restrict__ grdb,
                                                 float* __restrict__ part) {
    __shared__ float red[17 * 256];   // [r][dxi][l] at ((r*17+dxi)*64+l), 17408 B
    int b = blockIdx.x;
    int dyi = b >> 6, csl = (b >> 3) & 7, hq = b & 7;
    int t = threadIdx.x;
    int wv = t >> 6, l = t & 63;
    int m16 = l & 15, q = l >> 4, jl = q >> 1, c8 = q & 1;
    int wbase = wv * 16;

    for (int i = t; i < 17 * 64; i += 256) *(floatx4*)&red[i * 4] = (floatx4)0.f;

    floatx4 acc[17];
    #pragma unroll
    for (int d = 0; d < 17; ++d) acc[d] = (floatx4)0.f;

    const unsigned short* sbase = satp + (size_t)csl * SATP_SLICE_U16
                                + ((wbase + jl) * 16 + m16) * 16 + c8 * 8;
    const unsigned short* gbase = grdb + (size_t)csl * GRD_SLICE_U16
                                + ((wbase + jl) * 16 + m16) * 16 + c8 * 8;

    int h0 = hq * 8;
    #pragma unroll 1
    for (int hh = 0; hh < 8; ++hh) {
        int h = h0 + hh;
        int hs = h + dyi - 8;
        if ((unsigned)hs >= (unsigned)HH) continue;   // block-uniform
        const unsigned short* gp = gbase + (size_t)h * (64 * 256);
        bf16x8 B[8];
        #pragma unroll
        for (int bi = 0; bi < 8; ++bi) B[bi] = *(const bf16x8*)(gp + bi * 512);
        const unsigned short* ap = sbase + (size_t)hs * (80 * 256);
        #pragma unroll
        for (int wo = 0; wo < 31; ++wo) {            // slot = wbase + wo (+jl)
            bf16x8 A = *(const bf16x8*)(ap + wo * 256);
            #pragma unroll
            for (int bi = 0; bi < 8; ++bi) {
                int dxi = wo - 2 * bi;               // compile-time after unroll
                if (dxi >= 0 && dxi <= 16)
                    acc[dxi] = __builtin_amdgcn_mfma_f32_16x16x32_bf16(A, B[bi], acc[dxi], 0, 0, 0);
            }
        }
    }

    __syncthreads();            // red[] zeroing visible to all
    #pragma unroll
    for (int dxi = 0; dxi < 17; ++dxi) {
        #pragma unroll
        for (int r = 0; r < 4; ++r)
            atomicAdd(&red[((r * 17 + dxi) * 64) + l], acc[dxi][r]);
    }
    __syncthreads();
    float* pb = part + (size_t)b * PART_F_BLK;
    for (int i = t; i < 17 * 64; i += 256)
        *(floatx4*)&pb[i * 4] = *(floatx4*)&red[i * 4];
}

// ---------------- K4: reduce partials over (csl,hq) -> raw ----------------
__global__ void k_reduce(const float* __restrict__ part, float* __restrict__ ws) {
    int b = blockIdx.x;            // 289
    int dyi = b / 17, dxi = b % 17;
    int t = threadIdx.x;
    int l = t & 63, r = t >> 6;
    const float* p = part + (size_t)dyi * 64 * PART_F_BLK + (r * 17 + dxi) * 64 + l;
    float s = 0.f;
    #pragma unroll 8
    for (int j = 0; j < 64; ++j) s += p[(size_t)j * PART_F_BLK];
    int n = l & 15, qq = l >> 4;
    int m = qq * 4 + r;
    ws[OFF_RAW + (size_t)(m * 16 + n) * NSHIFT + dyi * 17 + dxi] = s;
}

// ---------------- K5: epilogue -> 3 scalars ----------------
__global__ void k_final(const float* __restrict__ ws, float* __restrict__ out) {
    const float* raw   = ws + OFF_RAW;
    const float* scale = ws + OFF_SCALE;
    const float* norms = ws + OFF_NORM;
    __shared__ float dist_s[256];
    __shared__ float pos_s[16];
    __shared__ float red[256];
    __shared__ float minv[16];
    int t = threadIdx.x;          // t = m*16 + n
    int m = t >> 4, n = t & 15;

    float best = -1e30f;
    const float* rp = raw + (size_t)t * NSHIFT;
    const float* sp = scale + m * NSHIFT;
    for (int s = 0; s < NSHIFT; ++s) best = fmaxf(best, rp[s] * sp[s]);
    float Ng  = sqrtf(norms[n]);
    float sim = best / fmaxf(Ng, 1e-12f);
    float d   = 2.f - 2.f * sim;
    dist_s[t] = d;
    if (m == n) pos_s[m] = d;
    __syncthreads();

    float x1 = (pos_s[n] - d) * 10.f;
    float x2 = (pos_s[m] - d) * 10.f;
    float sp1 = x1 > 20.f ? x1 : log1pf(expf(x1));
    float sp2 = x2 > 20.f ? x2 : log1pf(expf(x2));
    red[t] = sp1 + sp2;
    __syncthreads();
    for (int off = 128; off; off >>= 1) {
        if (t < off) red[t] += red[t + off];
        __syncthreads();
    }
    if (t < 16) {
        float mv = 1e30f;
        for (int nn = 0; nn < 16; ++nn) mv = fminf(mv, dist_s[t * 16 + nn]);
        minv[t] = mv;
    }
    __syncthreads();
    if (t == 0) {
        float psum = 0.f, msum = 0.f;
        for (int qq = 0; qq < 16; ++qq) { psum += pos_s[qq]; msum += minv[qq]; }
        out[0] = red[0] / 48.f;
        out[1] = psum / 16.f;
        out[2] = msum / 16.f;
    }
}

extern "C" void kernel_launch(void* const* d_in, const int* in_sizes, int n_in,
                              void* d_out, int out_size, void* d_ws, size_t ws_size,
                              hipStream_t stream) {
    const float* sat = (const float*)d_in[0];
    const float* grd = (const float*)d_in[1];
    float* out = (float*)d_out;
    float* ws  = (float*)d_ws;
    const unsigned short* satp = (const unsigned short*)((char*)d_ws + OFF_SATP_B);
    const unsigned short* grdb = (const unsigned short*)((char*)d_ws + OFF_GRDB_B);
    float* part = (float*)((char*)d_ws + OFF_PART_B);

    hipMemsetAsync(d_ws, 0, ZERO_BYTES, stream);   // raw (harmless) + norm
    k_prep  <<<2048,        256, 0, stream>>>(sat, grd, ws);
    k_scale <<<16 * NSHIFT, 256, 0, stream>>>(ws);
    k_corr  <<<NBLK_CORR,   256, 0, stream>>>(satp, grdb, part);
    k_reduce<<<NSHIFT,      256, 0, stream>>>(part, ws);
    k_final <<<1,           256, 0, stream>>>(ws, out);
}

// Round 5
// 353.173 us; speedup vs baseline: 1.9153x; 1.2349x over previous
//
#include <hip/hip_runtime.h>
#include <math.h>

#define CCH 128
#define HH 64
#define WW 64
#define SHD 17
#define NSHIFT (SHD*SHD)   // 289

// ---- workspace layout ----
// floats (index): raw 73984 | norm 16 | energy 65536 | scale 4624
#define OFF_RAW    0
#define OFF_NORM   73984
#define OFF_ENERGY 74000
#define OFF_SCALE  139536
// bytes:
#define OFF_SATP_B 576640                         // padded sat bf16: 8 slices x [h64][slot80][n16][c16]
#define SATP_SLICE_U16 (64*80*16*16)              // 1310720
#define OFF_GRDB_B (OFF_SATP_B + 8*SATP_SLICE_U16*2)        // 21548160
#define GRD_SLICE_U16 (64*64*16*16)               // 1048576
#define OFF_PART_B (OFF_GRDB_B + 8*GRD_SLICE_U16*2)         // 38325376
#define PART_F_BLK 4352                           // 17*256 floats per corr block
#define NBLK_CORR (17*64)                         // 1088  (hq8 x dyi17 x csl8)
#define ZERO_BYTES 296064                         // raw + norm

typedef __bf16 bf16x8 __attribute__((ext_vector_type(8)));
typedef float floatx4 __attribute__((ext_vector_type(4)));
typedef unsigned short ushort8 __attribute__((ext_vector_type(8)));

__device__ inline unsigned short f2bf(float f) {
    unsigned x = __float_as_uint(f);
    unsigned r = x + 0x7FFFu + ((x >> 16) & 1u);   // RNE
    return (unsigned short)(r >> 16);
}

// ---------------- K1: convert + transpose + norms/energy ----------------
// sat -> padded [csl][h][slot=8+w][n][c], grd -> [csl][h][w][n][c]
// grid: 2 tensors * 16 samples * 64 h = 2048 blocks, 256 threads
__global__ __launch_bounds__(256) void k_prep(const float* __restrict__ sat,
                                              const float* __restrict__ grd,
                                              float* __restrict__ ws) {
    __shared__ unsigned short tile[64 * 128];   // [w][16 chunks xor-swizzled][8]
    __shared__ float ered[4][64];
    int b = blockIdx.x;
    int tensor = b >> 10, n = (b >> 6) & 15, h = b & 63;
    const float* src = tensor ? grd : sat;
    unsigned short* dstS = (unsigned short*)((char*)ws + OFF_SATP_B);
    unsigned short* dstG = (unsigned short*)((char*)ws + OFF_GRDB_B);
    int t = threadIdx.x;
    int w = t & 63, cg4 = t >> 6;

    float esum = 0.f;
    #pragma unroll
    for (int it = 0; it < 4; ++it) {
        int cg = it * 4 + cg4;      // c-octet index (8 channels)
        int cb = cg * 8;
        ushort8 pack;
        #pragma unroll
        for (int j = 0; j < 8; ++j) {
            float v = src[(((size_t)n * CCH + cb + j) * HH + h) * WW + w];
            esum = fmaf(v, v, esum);
            pack[j] = f2bf(v);
        }
        int chunk = cg ^ (w & 15);
        *(ushort8*)&tile[(w * 16 + chunk) * 8] = pack;
    }
    ered[cg4][w] = esum;
    __syncthreads();
    if (t < 64) {
        float e = ered[0][t] + ered[1][t] + ered[2][t] + ered[3][t];
        if (tensor == 0) {
            ws[OFF_ENERGY + ((size_t)n * HH + h) * WW + t] = e;
        } else {
            #pragma unroll
            for (int off = 32; off; off >>= 1) e += __shfl_xor(e, off);
            if (t == 0) atomicAdd(&ws[OFF_NORM + n], e);
        }
    }
    // zero w-pad slots of sat (slots 0..7 and 72..79) for this (h, n)
    if (tensor == 0) {
        int cslz = t >> 5, i5 = t & 31;
        int s8 = i5 & 15, cz = i5 >> 4;
        int p = (s8 < 8) ? s8 : (s8 + 64);
        *(ushort8*)&dstS[(size_t)cslz * SATP_SLICE_U16 +
                         (((size_t)h * 80 + p) * 16 + n) * 16 + cz * 8] = (ushort8)0;
    }
    // transposed data write
    int wq = t >> 2, q = t & 3;
    #pragma unroll
    for (int c4 = 0; c4 < 4; ++c4) {
        int cg = q * 4 + c4;
        int csl = cg >> 1, c8 = cg & 1;
        int chunk = cg ^ (wq & 15);
        ushort8 val = *(ushort8*)&tile[(wq * 16 + chunk) * 8];
        if (tensor == 0) {
            *(ushort8*)&dstS[(size_t)csl * SATP_SLICE_U16 +
                             (((size_t)h * 80 + 8 + wq) * 16 + n) * 16 + c8 * 8] = val;
        } else {
            *(ushort8*)&dstG[(size_t)csl * GRD_SLICE_U16 +
                             (((size_t)h * 64 + wq) * 16 + n) * 16 + c8 * 8] = val;
        }
    }
}

// ---------------- K2: windowed energy -> scale (separable, 1 block/m) ----
__global__ __launch_bounds__(320) void k_scale(float* __restrict__ ws) {
    __shared__ float E[64 * 64];     // 16 KB
    __shared__ float R[64 * 17];     // row-window sums
    int m = blockIdx.x;
    int t = threadIdx.x;
    const float* energy = ws + OFF_ENERGY + (size_t)m * 4096;
    float* scale = ws + OFF_SCALE + (size_t)m * NSHIFT;
    for (int i = t; i < 4096; i += 320) E[i] = energy[i];
    __syncthreads();
    // R[y][j] = sum_{x in [j-8, j+56) ∩ [0,64)} E[y][x]
    for (int i = t; i < 64 * 17; i += 320) {
        int y = i / 17, j = i % 17;
        int x0 = max(0, j - 8), x1 = min(64, j + 56);
        float s = 0.f;
        for (int x = x0; x < x1; ++x) s += E[y * 64 + x];
        R[i] = s;
    }
    __syncthreads();
    // S[i][j] = sum_{y in [i-8, i+56) ∩ [0,64)} R[y][j]
    for (int idx = t; idx < NSHIFT; idx += 320) {
        int ii = idx / 17, j = idx % 17;
        int y0 = max(0, ii - 8), y1 = min(64, ii + 56);
        float s = 0.f;
        for (int y = y0; y < y1; ++y) s += R[y * 17 + j];
        scale[idx] = 1.f / fmaxf(sqrtf(s), 1e-12f);
    }
}

// ---------------- K3: MFMA cross-correlation, direct L2 loads ----------
// grid: b -> csl = b&7 (XCD round-robin is on LOW bits!), dyi = (b>>3)%17,
//       hq = (b>>3)/17.  4 waves; wave wv owns grd w in [wv*16,wv*16+16) as
//       8 w-pairs; K = 32 = 16c x 2w. acc[17] floatx4. LDS only for the
//       cross-wave reduce; plain partial store (no global atomics).
__global__ __launch_bounds__(256, 3) void k_corr(const unsigned short* __restrict__ satp,
                                                 const unsigned short* __restrict__ grdb,
                                                 float* __restrict__ part) {
    __shared__ float red[17 * 256];   // [r][dxi][l], 17408 B
    int b = blockIdx.x;
    int csl = b & 7;
    int r2  = b >> 3;
    int dyi = r2 % 17;
    int hq  = r2 / 17;             // 0..7
    int t = threadIdx.x;
    int wv = t >> 6, l = t & 63;
    int m16 = l & 15, q = l >> 4, jl = q >> 1, c8 = q & 1;
    int wbase = wv * 16;

    for (int i = t; i < 17 * 64; i += 256) *(floatx4*)&red[i * 4] = (floatx4)0.f;

    floatx4 acc[17];
    #pragma unroll
    for (int d = 0; d < 17; ++d) acc[d] = (floatx4)0.f;

    const unsigned short* sbase = satp + (size_t)csl * SATP_SLICE_U16
                                + ((wbase + jl) * 16 + m16) * 16 + c8 * 8;
    const unsigned short* gbase = grdb + (size_t)csl * GRD_SLICE_U16
                                + ((wbase + jl) * 16 + m16) * 16 + c8 * 8;

    int h0 = hq * 8;
    // valid h range: hs = h + dyi - 8 in [0,64)
    int hl = max(0, 8 - dyi - h0), hu = min(8, 72 - dyi - h0);
    #pragma unroll 1
    for (int hh = hl; hh < hu; ++hh) {
        int h = h0 + hh;
        int hs = h + dyi - 8;
        const unsigned short* gp = gbase + (size_t)h * (64 * 256);
        bf16x8 B[8];
        #pragma unroll
        for (int bi = 0; bi < 8; ++bi) B[bi] = *(const bf16x8*)(gp + bi * 512);
        const unsigned short* ap = sbase + (size_t)hs * (80 * 256);
        #pragma unroll
        for (int wo = 0; wo < 31; ++wo) {            // slot = wbase + wo (+jl)
            bf16x8 A = *(const bf16x8*)(ap + wo * 256);
            #pragma unroll
            for (int bi = 0; bi < 8; ++bi) {
                int dxi = wo - 2 * bi;               // compile-time after unroll
                if (dxi >= 0 && dxi <= 16)
                    acc[dxi] = __builtin_amdgcn_mfma_f32_16x16x32_bf16(A, B[bi], acc[dxi], 0, 0, 0);
            }
        }
    }

    __syncthreads();            // red[] zeroing visible to all
    #pragma unroll
    for (int dxi = 0; dxi < 17; ++dxi) {
        #pragma unroll
        for (int r = 0; r < 4; ++r)
            atomicAdd(&red[((r * 17 + dxi) * 64) + l], acc[dxi][r]);
    }
    __syncthreads();
    float* pb = part + (size_t)b * PART_F_BLK;
    for (int i = t; i < 17 * 64; i += 256)
        *(floatx4*)&pb[i * 4] = *(floatx4*)&red[i * 4];
}

// ---------------- K4: reduce partials over (csl,hq) -> raw ----------------
__global__ void k_reduce(const float* __restrict__ part, float* __restrict__ ws) {
    int b = blockIdx.x;            // 289
    int dyi = b / 17, dxi = b % 17;
    int t = threadIdx.x;
    int l = t & 63, r = t >> 6;
    float s = 0.f;
    #pragma unroll 8
    for (int j = 0; j < 64; ++j) {
        int cslj = j & 7, hqj = j >> 3;
        size_t bb = (size_t)(hqj * 17 + dyi) * 8 + cslj;
        s += part[bb * PART_F_BLK + (r * 17 + dxi) * 64 + l];
    }
    int n = l & 15, qq = l >> 4;
    int m = qq * 4 + r;
    ws[OFF_RAW + (size_t)(m * 16 + n) * NSHIFT + dyi * 17 + dxi] = s;
}

// ---------------- K5: epilogue -> 3 scalars ----------------
__global__ void k_final(const float* __restrict__ ws, float* __restrict__ out) {
    const float* raw   = ws + OFF_RAW;
    const float* scale = ws + OFF_SCALE;
    const float* norms = ws + OFF_NORM;
    __shared__ float dist_s[256];
    __shared__ float pos_s[16];
    __shared__ float red[256];
    __shared__ float minv[16];
    int t = threadIdx.x;          // t = m*16 + n
    int m = t >> 4, n = t & 15;

    float best = -1e30f;
    const float* rp = raw + (size_t)t * NSHIFT;
    const float* sp = scale + m * NSHIFT;
    for (int s = 0; s < NSHIFT; ++s) best = fmaxf(best, rp[s] * sp[s]);
    float Ng  = sqrtf(norms[n]);
    float sim = best / fmaxf(Ng, 1e-12f);
    float d   = 2.f - 2.f * sim;
    dist_s[t] = d;
    if (m == n) pos_s[m] = d;
    __syncthreads();

    float x1 = (pos_s[n] - d) * 10.f;
    float x2 = (pos_s[m] - d) * 10.f;
    float sp1 = x1 > 20.f ? x1 : log1pf(expf(x1));
    float sp2 = x2 > 20.f ? x2 : log1pf(expf(x2));
    red[t] = sp1 + sp2;
    __syncthreads();
    for (int off = 128; off; off >>= 1) {
        if (t < off) red[t] += red[t + off];
        __syncthreads();
    }
    if (t < 16) {
        float mv = 1e30f;
        for (int nn = 0; nn < 16; ++nn) mv = fminf(mv, dist_s[t * 16 + nn]);
        minv[t] = mv;
    }
    __syncthreads();
    if (t == 0) {
        float psum = 0.f, msum = 0.f;
        for (int qq = 0; qq < 16; ++qq) { psum += pos_s[qq]; msum += minv[qq]; }
        out[0] = red[0] / 48.f;
        out[1] = psum / 16.f;
        out[2] = msum / 16.f;
    }
}

extern "C" void kernel_launch(void* const* d_in, const int* in_sizes, int n_in,
                              void* d_out, int out_size, void* d_ws, size_t ws_size,
                              hipStream_t stream) {
    const float* sat = (const float*)d_in[0];
    const float* grd = (const float*)d_in[1];
    float* out = (float*)d_out;
    float* ws  = (float*)d_ws;
    const unsigned short* satp = (const unsigned short*)((char*)d_ws + OFF_SATP_B);
    const unsigned short* grdb = (const unsigned short*)((char*)d_ws + OFF_GRDB_B);
    float* part = (float*)((char*)d_ws + OFF_PART_B);

    hipMemsetAsync(d_ws, 0, ZERO_BYTES, stream);   // raw + norm
    k_prep  <<<2048,      256, 0, stream>>>(sat, grd, ws);
    k_scale <<<16,        320, 0, stream>>>(ws);
    k_corr  <<<NBLK_CORR, 256, 0, stream>>>(satp, grdb, part);
    k_reduce<<<NSHIFT,    256, 0, stream>>>(part, ws);
    k_final <<<1,         256, 0, stream>>>(ws, out);
}

// Round 6
// 330.386 us; speedup vs baseline: 2.0474x; 1.0690x over previous
//
#include <hip/hip_runtime.h>
#include <math.h>

#define CCH 128
#define HH 64
#define WW 64
#define SHD 17
#define NSHIFT (SHD*SHD)   // 289

// ---- workspace layout ----
// floats (index): raw 73984 | norm 16 | energy 65536 | scale 4624
#define OFF_RAW    0
#define OFF_NORM   73984
#define OFF_ENERGY 74000
#define OFF_SCALE  139536
// bytes:
#define OFF_SATP_B 576640                         // padded sat bf16: 8 slices x [h64][slot80][n16][c16]
#define SATP_SLICE_U16 (64*80*16*16)              // 1310720
#define OFF_GRDB_B (OFF_SATP_B + 8*SATP_SLICE_U16*2)        // 21548160
#define GRD_SLICE_U16 (64*64*16*16)               // 1048576
#define OFF_PART_B (OFF_GRDB_B + 8*GRD_SLICE_U16*2)         // 38325376
#define PART_F_BLK 4352                           // 17*256 floats per corr block
#define NBLK_CORR (17*64)                         // 1088  (hq8 x dyi17 x csl8)
#define ZERO_BYTES 296064                         // raw + norm

typedef __bf16 bf16x8 __attribute__((ext_vector_type(8)));
typedef float floatx4 __attribute__((ext_vector_type(4)));
typedef unsigned short ushort8 __attribute__((ext_vector_type(8)));

__device__ inline unsigned short f2bf(float f) {
    unsigned x = __float_as_uint(f);
    unsigned r = x + 0x7FFFu + ((x >> 16) & 1u);   // RNE
    return (unsigned short)(r >> 16);
}

// ---------------- K1: convert + transpose + norms/energy ----------------
// sat -> padded [csl][h][slot=8+w][n][c], grd -> [csl][h][w][n][c]
// grid: 2 tensors * 16 samples * 64 h = 2048 blocks, 256 threads
__global__ __launch_bounds__(256) void k_prep(const float* __restrict__ sat,
                                              const float* __restrict__ grd,
                                              float* __restrict__ ws) {
    __shared__ unsigned short tile[64 * 128];   // [w][16 chunks xor-swizzled][8]
    __shared__ float ered[4][64];
    int b = blockIdx.x;
    int tensor = b >> 10, n = (b >> 6) & 15, h = b & 63;
    const float* src = tensor ? grd : sat;
    unsigned short* dstS = (unsigned short*)((char*)ws + OFF_SATP_B);
    unsigned short* dstG = (unsigned short*)((char*)ws + OFF_GRDB_B);
    int t = threadIdx.x;
    int w = t & 63, cg4 = t >> 6;

    float esum = 0.f;
    #pragma unroll
    for (int it = 0; it < 4; ++it) {
        int cg = it * 4 + cg4;      // c-octet index (8 channels)
        int cb = cg * 8;
        ushort8 pack;
        #pragma unroll
        for (int j = 0; j < 8; ++j) {
            float v = src[(((size_t)n * CCH + cb + j) * HH + h) * WW + w];
            esum = fmaf(v, v, esum);
            pack[j] = f2bf(v);
        }
        int chunk = cg ^ (w & 15);
        *(ushort8*)&tile[(w * 16 + chunk) * 8] = pack;
    }
    ered[cg4][w] = esum;
    __syncthreads();
    if (t < 64) {
        float e = ered[0][t] + ered[1][t] + ered[2][t] + ered[3][t];
        if (tensor == 0) {
            ws[OFF_ENERGY + ((size_t)n * HH + h) * WW + t] = e;
        } else {
            #pragma unroll
            for (int off = 32; off; off >>= 1) e += __shfl_xor(e, off);
            if (t == 0) atomicAdd(&ws[OFF_NORM + n], e);
        }
    }
    // zero w-pad slots of sat (slots 0..7 and 72..79) for this (h, n)
    if (tensor == 0) {
        int cslz = t >> 5, i5 = t & 31;
        int s8 = i5 & 15, cz = i5 >> 4;
        int p = (s8 < 8) ? s8 : (s8 + 64);
        *(ushort8*)&dstS[(size_t)cslz * SATP_SLICE_U16 +
                         (((size_t)h * 80 + p) * 16 + n) * 16 + cz * 8] = (ushort8)0;
    }
    // transposed data write
    int wq = t >> 2, q = t & 3;
    #pragma unroll
    for (int c4 = 0; c4 < 4; ++c4) {
        int cg = q * 4 + c4;
        int csl = cg >> 1, c8 = cg & 1;
        int chunk = cg ^ (wq & 15);
        ushort8 val = *(ushort8*)&tile[(wq * 16 + chunk) * 8];
        if (tensor == 0) {
            *(ushort8*)&dstS[(size_t)csl * SATP_SLICE_U16 +
                             (((size_t)h * 80 + 8 + wq) * 16 + n) * 16 + c8 * 8] = val;
        } else {
            *(ushort8*)&dstG[(size_t)csl * GRD_SLICE_U16 +
                             (((size_t)h * 64 + wq) * 16 + n) * 16 + c8 * 8] = val;
        }
    }
}

// ---------------- K2: windowed energy -> scale (separable, 1 block/m) ----
__global__ __launch_bounds__(320) void k_scale(float* __restrict__ ws) {
    __shared__ float E[64 * 64];     // 16 KB
    __shared__ float R[64 * 17];     // row-window sums
    int m = blockIdx.x;
    int t = threadIdx.x;
    const float* energy = ws + OFF_ENERGY + (size_t)m * 4096;
    float* scale = ws + OFF_SCALE + (size_t)m * NSHIFT;
    for (int i = t; i < 4096; i += 320) E[i] = energy[i];
    __syncthreads();
    // R[y][j] = sum_{x in [j-8, j+56) ∩ [0,64)} E[y][x]
    for (int i = t; i < 64 * 17; i += 320) {
        int y = i / 17, j = i % 17;
        int x0 = max(0, j - 8), x1 = min(64, j + 56);
        float s = 0.f;
        for (int x = x0; x < x1; ++x) s += E[y * 64 + x];
        R[i] = s;
    }
    __syncthreads();
    // S[i][j] = sum_{y in [i-8, i+56) ∩ [0,64)} R[y][j]
    for (int idx = t; idx < NSHIFT; idx += 320) {
        int ii = idx / 17, j = idx % 17;
        int y0 = max(0, ii - 8), y1 = min(64, ii + 56);
        float s = 0.f;
        for (int y = y0; y < y1; ++y) s += R[y * 17 + j];
        scale[idx] = 1.f / fmaxf(sqrtf(s), 1e-12f);
    }
}

// ---------------- K3: MFMA cross-correlation, direct L2 loads ----------
// grid: b -> csl = b&7 (XCD round-robin on LOW bits), dyi = (b>>3)%17,
//       hq = (b>>3)/17.  4 waves; wave wv owns grd w in [wv*16,wv*16+16) as
//       8 w-pairs; K = 32 = 16c x 2w.  acc[17] floatx4.
//       Rolling register prefetch (depth 6) keeps ~6 A-loads in flight per
//       wave to cover ~200cyc L2 latency (R5: VGPR=72 -> compiler had no
//       prefetch registers, MfmaUtil 15.8%).
__global__ __launch_bounds__(256, 3) void k_corr(const unsigned short* __restrict__ satp,
                                                 const unsigned short* __restrict__ grdb,
                                                 float* __restrict__ part) {
    __shared__ float red[17 * 256];   // [r][dxi][l], 17408 B
    int b = blockIdx.x;
    int csl = b & 7;
    int r2  = b >> 3;
    int dyi = r2 % 17;
    int hq  = r2 / 17;             // 0..7
    int t = threadIdx.x;
    int wv = t >> 6, l = t & 63;
    int m16 = l & 15, q = l >> 4, jl = q >> 1, c8 = q & 1;
    int wbase = wv * 16;

    for (int i = t; i < 17 * 64; i += 256) *(floatx4*)&red[i * 4] = (floatx4)0.f;

    floatx4 acc[17];
    #pragma unroll
    for (int d = 0; d < 17; ++d) acc[d] = (floatx4)0.f;

    const unsigned short* sbase = satp + (size_t)csl * SATP_SLICE_U16
                                + ((wbase + jl) * 16 + m16) * 16 + c8 * 8;
    const unsigned short* gbase = grdb + (size_t)csl * GRD_SLICE_U16
                                + ((wbase + jl) * 16 + m16) * 16 + c8 * 8;

    int h0 = hq * 8;
    // valid h range: hs = h + dyi - 8 in [0,64)
    int hl = max(0, 8 - dyi - h0), hu = min(8, 72 - dyi - h0);
    #pragma unroll 1
    for (int hh = hl; hh < hu; ++hh) {
        int h = h0 + hh;
        int hs = h + dyi - 8;
        const unsigned short* gp = gbase + (size_t)h * (64 * 256);
        const unsigned short* ap = sbase + (size_t)hs * (80 * 256);
        bf16x8 B[8];
        #pragma unroll
        for (int bi = 0; bi < 8; ++bi) B[bi] = *(const bf16x8*)(gp + bi * 512);
        bf16x8 Ar[6];
        #pragma unroll
        for (int i = 0; i < 6; ++i) Ar[i] = *(const bf16x8*)(ap + i * 256);
        #pragma unroll
        for (int wo = 0; wo < 31; ++wo) {            // slot = wbase + wo (+jl)
            bf16x8 A = Ar[wo % 6];
            if (wo + 6 < 31) Ar[wo % 6] = *(const bf16x8*)(ap + (wo + 6) * 256);
            #pragma unroll
            for (int bi = 0; bi < 8; ++bi) {
                int dxi = wo - 2 * bi;               // compile-time after unroll
                if (dxi >= 0 && dxi <= 16)
                    acc[dxi] = __builtin_amdgcn_mfma_f32_16x16x32_bf16(A, B[bi], acc[dxi], 0, 0, 0);
            }
        }
    }

    __syncthreads();            // red[] zeroing visible to all
    #pragma unroll
    for (int dxi = 0; dxi < 17; ++dxi) {
        #pragma unroll
        for (int r = 0; r < 4; ++r)
            atomicAdd(&red[((r * 17 + dxi) * 64) + l], acc[dxi][r]);
    }
    __syncthreads();
    float* pb = part + (size_t)b * PART_F_BLK;
    for (int i = t; i < 17 * 64; i += 256)
        *(floatx4*)&pb[i * 4] = *(floatx4*)&red[i * 4];
}

// ---------------- K4: reduce partials over (csl,hq) -> raw ----------------
__global__ void k_reduce(const float* __restrict__ part, float* __restrict__ ws) {
    int b = blockIdx.x;            // 289
    int dyi = b / 17, dxi = b % 17;
    int t = threadIdx.x;
    int l = t & 63, r = t >> 6;
    float s = 0.f;
    #pragma unroll 8
    for (int j = 0; j < 64; ++j) {
        int cslj = j & 7, hqj = j >> 3;
        size_t bb = (size_t)(hqj * 17 + dyi) * 8 + cslj;
        s += part[bb * PART_F_BLK + (r * 17 + dxi) * 64 + l];
    }
    int n = l & 15, qq = l >> 4;
    int m = qq * 4 + r;
    ws[OFF_RAW + (size_t)(m * 16 + n) * NSHIFT + dyi * 17 + dxi] = s;
}

// ---------------- K5: epilogue -> 3 scalars ----------------
__global__ void k_final(const float* __restrict__ ws, float* __restrict__ out) {
    const float* raw   = ws + OFF_RAW;
    const float* scale = ws + OFF_SCALE;
    const float* norms = ws + OFF_NORM;
    __shared__ float dist_s[256];
    __shared__ float pos_s[16];
    __shared__ float red[256];
    __shared__ float minv[16];
    int t = threadIdx.x;          // t = m*16 + n
    int m = t >> 4, n = t & 15;

    float best = -1e30f;
    const float* rp = raw + (size_t)t * NSHIFT;
    const float* sp = scale + m * NSHIFT;
    for (int s = 0; s < NSHIFT; ++s) best = fmaxf(best, rp[s] * sp[s]);
    float Ng  = sqrtf(norms[n]);
    float sim = best / fmaxf(Ng, 1e-12f);
    float d   = 2.f - 2.f * sim;
    dist_s[t] = d;
    if (m == n) pos_s[m] = d;
    __syncthreads();

    float x1 = (pos_s[n] - d) * 10.f;
    float x2 = (pos_s[m] - d) * 10.f;
    float sp1 = x1 > 20.f ? x1 : log1pf(expf(x1));
    float sp2 = x2 > 20.f ? x2 : log1pf(expf(x2));
    red[t] = sp1 + sp2;
    __syncthreads();
    for (int off = 128; off; off >>= 1) {
        if (t < off) red[t] += red[t + off];
        __syncthreads();
    }
    if (t < 16) {
        float mv = 1e30f;
        for (int nn = 0; nn < 16; ++nn) mv = fminf(mv, dist_s[t * 16 + nn]);
        minv[t] = mv;
    }
    __syncthreads();
    if (t == 0) {
        float psum = 0.f, msum = 0.f;
        for (int qq = 0; qq < 16; ++qq) { psum += pos_s[qq]; msum += minv[qq]; }
        out[0] = red[0] / 48.f;
        out[1] = psum / 16.f;
        out[2] = msum / 16.f;
    }
}

extern "C" void kernel_launch(void* const* d_in, const int* in_sizes, int n_in,
                              void* d_out, int out_size, void* d_ws, size_t ws_size,
                              hipStream_t stream) {
    const float* sat = (const float*)d_in[0];
    const float* grd = (const float*)d_in[1];
    float* out = (float*)d_out;
    float* ws  = (float*)d_ws;
    const unsigned short* satp = (const unsigned short*)((char*)d_ws + OFF_SATP_B);
    const unsigned short* grdb = (const unsigned short*)((char*)d_ws + OFF_GRDB_B);
    float* part = (float*)((char*)d_ws + OFF_PART_B);

    hipMemsetAsync(d_ws, 0, ZERO_BYTES, stream);   // raw + norm
    k_prep  <<<2048,      256, 0, stream>>>(sat, grd, ws);
    k_scale <<<16,        320, 0, stream>>>(ws);
    k_corr  <<<NBLK_CORR, 256, 0, stream>>>(satp, grdb, part);
    k_reduce<<<NSHIFT,    256, 0, stream>>>(part, ws);
    k_final <<<1,         256, 0, stream>>>(ws, out);
}

// Round 7
// 313.513 us; speedup vs baseline: 2.1576x; 1.0538x over previous
//
#include <hip/hip_runtime.h>
#include <math.h>

#define CCH 128
#define HH 64
#define WW 64
#define SHD 17
#define NSHIFT (SHD*SHD)   // 289

// ---- workspace layout ----
// floats (index): raw 73984 | norm 16 | energy 65536 | scale 4624
#define OFF_RAW    0
#define OFF_NORM   73984
#define OFF_ENERGY 74000
#define OFF_SCALE  139536
// bytes:
#define OFF_SATP_B 576640                         // padded sat bf16: 8 slices x [h64][slot80][n16][c16]
#define SATP_SLICE_U16 (64*80*16*16)              // 1310720
#define OFF_GRDB_B (OFF_SATP_B + 8*SATP_SLICE_U16*2)        // 21548160
#define GRD_SLICE_U16 (64*64*16*16)               // 1048576
#define OFF_PART_B (OFF_GRDB_B + 8*GRD_SLICE_U16*2)         // 38325376
#define PART_F_BLK 4352                           // 17*256 floats per corr block
#define NBLK_CORR (17*4*8)                        // 544: csl = b&7, dyi = (b>>3)%17, hq = (b>>3)/17
#define ZERO_BYTES 558144                         // raw + norm + energy (energy now atomic-accumulated)

typedef __bf16 bf16x8 __attribute__((ext_vector_type(8)));
typedef float floatx4 __attribute__((ext_vector_type(4)));
typedef unsigned short ushort8 __attribute__((ext_vector_type(8)));

#define AS1 __attribute__((address_space(1)))
#define AS3 __attribute__((address_space(3)))

__device__ inline unsigned short f2bf(float f) {
    unsigned x = __float_as_uint(f);
    unsigned r = x + 0x7FFFu + ((x >> 16) & 1u);   // RNE
    return (unsigned short)(r >> 16);
}

// ---------------- K1: convert + transpose + norms/energy (coalesced) -----
// grid: 1024 = tensor2 x h64 x csl8;  b: tensor = b>>9, h = (b>>3)&63, csl = b&7
// thread t: n = t>>4, wq = t&15 (w-quad). Reads 16 float4 rows; output is one
// contiguous 32 KB run per block. Energy via global atomicAdd (zeroed memset).
__global__ __launch_bounds__(256) void k_prep(const float* __restrict__ sat,
                                              const float* __restrict__ grd,
                                              float* __restrict__ ws) {
    __shared__ unsigned short tile[64 * 256];   // 32 KB: [w][ (n+w)&15 ][c16]
    int b = blockIdx.x;
    int tensor = b >> 9, h = (b >> 3) & 63, csl = b & 7;
    const float* src = tensor ? grd : sat;
    unsigned short* dstS = (unsigned short*)((char*)ws + OFF_SATP_B);
    unsigned short* dstG = (unsigned short*)((char*)ws + OFF_GRDB_B);
    int t = threadIdx.x;
    int n = t >> 4, wq = t & 15;

    float en0 = 0.f, en1 = 0.f, en2 = 0.f, en3 = 0.f;
    const float* base = src + ((size_t)(n * CCH + csl * 16) * 4096) + h * 64 + wq * 4;
    int w0 = wq * 4;
    #pragma unroll
    for (int c = 0; c < 16; ++c) {
        float4 v = *(const float4*)(base + (size_t)c * 4096);
        en0 = fmaf(v.x, v.x, en0); en1 = fmaf(v.y, v.y, en1);
        en2 = fmaf(v.z, v.z, en2); en3 = fmaf(v.w, v.w, en3);
        tile[(w0 + 0) * 256 + ((n + w0 + 0) & 15) * 16 + c] = f2bf(v.x);
        tile[(w0 + 1) * 256 + ((n + w0 + 1) & 15) * 16 + c] = f2bf(v.y);
        tile[(w0 + 2) * 256 + ((n + w0 + 2) & 15) * 16 + c] = f2bf(v.z);
        tile[(w0 + 3) * 256 + ((n + w0 + 3) & 15) * 16 + c] = f2bf(v.w);
    }

    // energy / norms (fp32, pre-rounding)
    if (tensor == 0) {
        float* eg = ws + OFF_ENERGY + ((size_t)n * 64 + h) * 64 + w0;
        atomicAdd(eg + 0, en0); atomicAdd(eg + 1, en1);
        atomicAdd(eg + 2, en2); atomicAdd(eg + 3, en3);
    } else {
        float s = en0 + en1 + en2 + en3;
        #pragma unroll
        for (int off = 8; off; off >>= 1) s += __shfl_xor(s, off);  // 16-lane group (same n)
        if (wq == 0) atomicAdd(&ws[OFF_NORM + n], s);
    }

    __syncthreads();
    // contiguous store: chunk o (16 B) -> w = o>>5, nn = (o>>1)&15, c8 = o&1
    unsigned short* dst = tensor
        ? dstG + (size_t)csl * GRD_SLICE_U16 + (size_t)h * 16384
        : dstS + (size_t)csl * SATP_SLICE_U16 + ((size_t)h * 80 + 8) * 256;
    #pragma unroll
    for (int i = 0; i < 8; ++i) {
        int o = i * 256 + t;
        int w = o >> 5, nn = (o >> 1) & 15, c8 = o & 1;
        ushort8 val = *(ushort8*)&tile[w * 256 + ((nn + w) & 15) * 16 + c8 * 8];
        *(ushort8*)&dst[(size_t)o * 8] = val;
    }
    // zero the 16 w-pad slots (8 KB) of this (h, csl) row
    if (tensor == 0) {
        ushort8 z = (ushort8)0;
        #pragma unroll
        for (int i = 0; i < 2; ++i) {
            int o = i * 256 + t;                  // 0..511 chunks of 16 B
            int slot = o >> 5, wi = o & 31;
            int ps = slot < 8 ? slot : slot + 64;
            *(ushort8*)&dstS[(size_t)csl * SATP_SLICE_U16 +
                             ((size_t)h * 80 + ps) * 256 + wi * 8] = z;
        }
    }
}

// ---------------- K2: windowed energy -> scale (separable, 1 block/m) ----
__global__ __launch_bounds__(320) void k_scale(float* __restrict__ ws) {
    __shared__ float E[64 * 64];     // 16 KB
    __shared__ float R[64 * 17];     // row-window sums
    int m = blockIdx.x;
    int t = threadIdx.x;
    const float* energy = ws + OFF_ENERGY + (size_t)m * 4096;
    float* scale = ws + OFF_SCALE + (size_t)m * NSHIFT;
    for (int i = t; i < 4096; i += 320) E[i] = energy[i];
    __syncthreads();
    for (int i = t; i < 64 * 17; i += 320) {
        int y = i / 17, j = i % 17;
        int x0 = max(0, j - 8), x1 = min(64, j + 56);
        float s = 0.f;
        for (int x = x0; x < x1; ++x) s += E[y * 64 + x];
        R[i] = s;
    }
    __syncthreads();
    for (int idx = t; idx < NSHIFT; idx += 320) {
        int ii = idx / 17, j = idx % 17;
        int y0 = max(0, ii - 8), y1 = min(64, ii + 56);
        float s = 0.f;
        for (int y = y0; y < y1; ++y) s += R[y * 17 + j];
        scale[idx] = 1.f / fmaxf(sqrtf(s), 1e-12f);
    }
}

// ---------------- K3: MFMA cross-correlation (m97-style LDS pipeline) ----
// grid 544: csl = b&7 (XCD low-bit swizzle), dyi = (b>>3)%17, hq = (b>>3)/17
// (16 h per block). Per hh: A row (40 KB) staged via global_load_lds into a
// double buffer (2x40960 = 81920 B -> exactly 2 blocks/CU); B fragments
// register-prefetched one hh ahead; MFMAs read A via ds_read_b128 (dense
// permutation of the 1 KB region -> conflict-free). One barrier per hh,
// amortized over 544 block-MFMAs. Epilogue reuses buffer 0 for reduction.
__global__ __launch_bounds__(256, 2) void k_corr(const unsigned short* __restrict__ satp,
                                                 const unsigned short* __restrict__ grdb,
                                                 float* __restrict__ part) {
    __shared__ alignas(16) unsigned char smem[81920];
    int b = blockIdx.x;
    int csl = b & 7;
    int r2  = b >> 3;
    int dyi = r2 % 17;
    int hq  = r2 / 17;             // 0..3
    int h0  = hq * 16;
    int t = threadIdx.x;
    int wv = t >> 6, l = t & 63;
    int m16 = l & 15, q = l >> 4, jl = q >> 1, c8 = q & 1;
    int wbase = wv * 16;

    const unsigned short* sats = satp + (size_t)csl * SATP_SLICE_U16;
    const unsigned short* grds = grdb + (size_t)csl * GRD_SLICE_U16;
    int hl = max(0, 8 - dyi - h0), hu = min(16, 72 - dyi - h0);

    floatx4 acc[17];
    #pragma unroll
    for (int d = 0; d < 17; ++d) acc[d] = (floatx4)0.f;

    // stage sat row hs (80 slots x 512 B) into buffer p; wave wv covers 10 KB
    #define STAGE(hs, p)                                                            \
        do {                                                                        \
            _Pragma("unroll")                                                       \
            for (int i_ = 0; i_ < 10; ++i_) {                                       \
                const unsigned short* g_ = sats + (size_t)(hs) * 20480              \
                                         + wv * 5120 + i_ * 512 + l * 8;            \
                __builtin_amdgcn_global_load_lds((AS1 void*)(unsigned short*)g_,    \
                    (AS3 void*)(smem + (p) * 40960 + wv * 10240 + i_ * 1024 + l * 16), \
                    16, 0, 0);                                                      \
            }                                                                       \
        } while (0)

    int hs0 = h0 + hl + dyi - 8;
    STAGE(hs0, 0);
    const unsigned short* goff = grds + ((wbase + jl) * 16 + m16) * 16 + c8 * 8;
    bf16x8 Bc[8], Bn[8];
    #pragma unroll
    for (int bi = 0; bi < 8; ++bi)
        Bc[bi] = *(const bf16x8*)(goff + (size_t)(h0 + hl) * 16384 + bi * 512);

    for (int hh = hl; hh < hu; ++hh) {
        __syncthreads();                         // stage(hh) + B loads drained
        int p = (hh - hl) & 1;
        if (hh + 1 < hu) {
            STAGE(hs0 + (hh - hl) + 1, p ^ 1);
            #pragma unroll
            for (int bi = 0; bi < 8; ++bi)
                Bn[bi] = *(const bf16x8*)(goff + (size_t)(h0 + hh + 1) * 16384 + bi * 512);
        }
        const unsigned char* aptr = smem + p * 40960 + jl * 512 + m16 * 32 + c8 * 16;
        #pragma unroll
        for (int wo = 0; wo < 31; ++wo) {        // slot = wbase + wo (+jl)
            bf16x8 A = *(const bf16x8*)(aptr + (wbase + wo) * 512);
            #pragma unroll
            for (int bi = 0; bi < 8; ++bi) {
                int dxi = wo - 2 * bi;           // compile-time after unroll
                if (dxi >= 0 && dxi <= 16)
                    acc[dxi] = __builtin_amdgcn_mfma_f32_16x16x32_bf16(A, Bc[bi], acc[dxi], 0, 0, 0);
            }
        }
        #pragma unroll
        for (int bi = 0; bi < 8; ++bi) Bc[bi] = Bn[bi];
    }
    #undef STAGE

    // cross-wave reduce in LDS (reuse buffer 0), plain partial store
    __syncthreads();
    float* red = (float*)smem;
    for (int i = t; i < 17 * 64; i += 256) *(floatx4*)&red[i * 4] = (floatx4)0.f;
    __syncthreads();
    #pragma unroll
    for (int dxi = 0; dxi < 17; ++dxi) {
        #pragma unroll
        for (int r = 0; r < 4; ++r)
            atomicAdd(&red[((r * 17 + dxi) * 64) + l], acc[dxi][r]);
    }
    __syncthreads();
    float* pb = part + (size_t)b * PART_F_BLK;
    for (int i = t; i < 17 * 64; i += 256)
        *(floatx4*)&pb[i * 4] = *(floatx4*)&red[i * 4];
}

// ---------------- K4: reduce partials over (csl,hq) -> raw ----------------
__global__ void k_reduce(const float* __restrict__ part, float* __restrict__ ws) {
    int b = blockIdx.x;            // 289
    int dyi = b / 17, dxi = b % 17;
    int t = threadIdx.x;
    int l = t & 63, r = t >> 6;
    float s = 0.f;
    #pragma unroll 8
    for (int j = 0; j < 32; ++j) {
        int cslj = j & 7, hqj = j >> 3;
        size_t bb = (size_t)(hqj * 17 + dyi) * 8 + cslj;
        s += part[bb * PART_F_BLK + (r * 17 + dxi) * 64 + l];
    }
    int n = l & 15, qq = l >> 4;
    int m = qq * 4 + r;
    ws[OFF_RAW + (size_t)(m * 16 + n) * NSHIFT + dyi * 17 + dxi] = s;
}

// ---------------- K5: epilogue -> 3 scalars ----------------
__global__ void k_final(const float* __restrict__ ws, float* __restrict__ out) {
    const float* raw   = ws + OFF_RAW;
    const float* scale = ws + OFF_SCALE;
    const float* norms = ws + OFF_NORM;
    __shared__ float dist_s[256];
    __shared__ float pos_s[16];
    __shared__ float red[256];
    __shared__ float minv[16];
    int t = threadIdx.x;          // t = m*16 + n
    int m = t >> 4, n = t & 15;

    float best = -1e30f;
    const float* rp = raw + (size_t)t * NSHIFT;
    const float* sp = scale + m * NSHIFT;
    for (int s = 0; s < NSHIFT; ++s) best = fmaxf(best, rp[s] * sp[s]);
    float Ng  = sqrtf(norms[n]);
    float sim = best / fmaxf(Ng, 1e-12f);
    float d   = 2.f - 2.f * sim;
    dist_s[t] = d;
    if (m == n) pos_s[m] = d;
    __syncthreads();

    float x1 = (pos_s[n] - d) * 10.f;
    float x2 = (pos_s[m] - d) * 10.f;
    float sp1 = x1 > 20.f ? x1 : log1pf(expf(x1));
    float sp2 = x2 > 20.f ? x2 : log1pf(expf(x2));
    red[t] = sp1 + sp2;
    __syncthreads();
    for (int off = 128; off; off >>= 1) {
        if (t < off) red[t] += red[t + off];
        __syncthreads();
    }
    if (t < 16) {
        float mv = 1e30f;
        for (int nn = 0; nn < 16; ++nn) mv = fminf(mv, dist_s[t * 16 + nn]);
        minv[t] = mv;
    }
    __syncthreads();
    if (t == 0) {
        float psum = 0.f, msum = 0.f;
        for (int qq = 0; qq < 16; ++qq) { psum += pos_s[qq]; msum += minv[qq]; }
        out[0] = red[0] / 48.f;
        out[1] = psum / 16.f;
        out[2] = msum / 16.f;
    }
}

extern "C" void kernel_launch(void* const* d_in, const int* in_sizes, int n_in,
                              void* d_out, int out_size, void* d_ws, size_t ws_size,
                              hipStream_t stream) {
    const float* sat = (const float*)d_in[0];
    const float* grd = (const float*)d_in[1];
    float* out = (float*)d_out;
    float* ws  = (float*)d_ws;
    const unsigned short* satp = (const unsigned short*)((char*)d_ws + OFF_SATP_B);
    const unsigned short* grdb = (const unsigned short*)((char*)d_ws + OFF_GRDB_B);
    float* part = (float*)((char*)d_ws + OFF_PART_B);

    hipMemsetAsync(d_ws, 0, ZERO_BYTES, stream);   // raw + norm + energy
    k_prep  <<<1024,      256, 0, stream>>>(sat, grd, ws);
    k_scale <<<16,        320, 0, stream>>>(ws);
    k_corr  <<<NBLK_CORR, 256, 0, stream>>>(satp, grdb, part);
    k_reduce<<<NSHIFT,    256, 0, stream>>>(part, ws);
    k_final <<<1,         256, 0, stream>>>(ws, out);
}